// Round 4
// baseline (190.031 us; speedup 1.0000x reference)
//
#include <hip/hip_runtime.h>
#include <hip/hip_bf16.h>
#include <math.h>

#define N_TOK 4096
#define DIM   1024

typedef __attribute__((ext_vector_type(8))) short s16x8;
typedef __attribute__((ext_vector_type(4))) float f32x4;

__device__ inline short to_bf16(float f) {
  union { float f; unsigned u; } v; v.f = f;
  unsigned r = v.u + 0x7FFFu + ((v.u >> 16) & 1u);   // RNE
  return (short)(r >> 16);
}

__device__ inline void gload16(const short* g, short* l) {
  __builtin_amdgcn_global_load_lds(
      (const __attribute__((address_space(1))) unsigned int*)g,
      (__attribute__((address_space(3))) unsigned int*)l, 16, 0, 0);
}

__device__ inline void bar() {
  asm volatile("" ::: "memory");
  __builtin_amdgcn_s_barrier();
  asm volatile("" ::: "memory");
}

// ---------------- cast fp32 -> bf16 ----------------
__global__ void cast_bf16_kernel(const float* __restrict__ in, short* __restrict__ out, int n) {
  int i = (blockIdx.x * blockDim.x + threadIdx.x) * 4;
  if (i >= n) return;
  float4 v = *reinterpret_cast<const float4*>(in + i);
  short4 o;
  o.x = to_bf16(v.x); o.y = to_bf16(v.y); o.z = to_bf16(v.z); o.w = to_bf16(v.w);
  *reinterpret_cast<short4*>(out + i) = o;
}

// ---------------- transpose + cast: in[R][C] fp32 -> out[C][R] bf16 ----------------
__global__ void transpose_cast_kernel(const float* __restrict__ in, short* __restrict__ out,
                                      int R, int C) {
  __shared__ float tile[32][33];
  int bx = blockIdx.x * 32, by = blockIdx.y * 32;
  int tx = threadIdx.x, ty = threadIdx.y;   // block (32,8)
  #pragma unroll
  for (int i = 0; i < 32; i += 8)
    tile[ty + i][tx] = in[(size_t)(by + ty + i) * C + (bx + tx)];
  __syncthreads();
  #pragma unroll
  for (int i = 0; i < 32; i += 8)
    out[(size_t)(bx + ty + i) * R + (by + tx)] = to_bf16(tile[tx][ty + i]);
}

__device__ inline float fast_tanh(float x) {
  float e = __expf(2.0f * x);
  return 1.0f - 2.0f / (e + 1.0f);
}

// ============ 256x256 tile, BK=64, 2-buf, 8-phase counted-vmcnt schedule ============
// Per K-tile: 4 phases {ds_read subtile ; stage 4 gloads ; bar ; setprio+16 MFMA ; bar}
// vmcnt(4) at end of P1 and P4 only (drains exactly the half-tile group needed next).
// LDS row layout permuted by halves so linear global_load_lds dest matches read order;
// 16B-chunk XOR swizzle (chunk ^ row&7) applied on global SOURCE + LDS-read side.
// EPI 0: +bias[col] -> bf16 ; EPI 1: +bias[row] -> bf16
// EPI 2: P=exp(tanh(.)/32) -> bf16 + atomic rowsum ; EPI 3: PV splitK (part / atomic)
template<int EPI>
__global__ __launch_bounds__(512, 2)
void gemm8p(const short* __restrict__ A, const short* __restrict__ B,
            int lda, int ldb, int NT, int nbx, int ldc,
            const float* __restrict__ aux, short* __restrict__ Cb,
            float* __restrict__ outF, const float* __restrict__ lsum,
            float* __restrict__ rowsum, float* __restrict__ part, int mode)
{
  __shared__ short lds[2 * 32768];     // 2 bufs x (A 256x64 + B 256x64) bf16 = 128 KB
  const int t    = threadIdx.x;
  const int lane = t & 63;
  const int w    = t >> 6;             // 8 waves: 2 (M) x 4 (N)
  const int wr   = w >> 2, wc = w & 3;
  const int l15  = lane & 15, l4 = lane >> 4;

  // bijective XCD swizzle (gridDim.x % 8 == 0)
  const int b   = blockIdx.x;
  const int cpx = (int)gridDim.x >> 3;
  const int swz = (b & 7) * cpx + (b >> 3);
  int bxx, byy, kc;
  if (EPI == 3) { kc = swz & 3; bxx = (swz >> 2) & 3; byy = swz >> 4; }
  else          { kc = 0; bxx = swz % nbx; byy = swz / nbx; }
  const int koff = kc * NT * 64;

  // ---- staging addresses: LDS slot p holds (A: row wr*128+mh*64+u ; B: wc*64+nh*32+u)
  // slot p = r*64 + w*8 + lr ; lane chunk pre-inverse-swizzled: c = (lane&7) ^ lr
  const int lr  = lane >> 3;
  const int cch = (lane & 7) ^ lr;
  const int q   = w * 8 + lr;          // [0,64)
  const short* gA0 = A + (size_t)(byy * 256 + q) * lda + koff + cch * 8;
  const short* gB0 = B + (size_t)(bxx * 256 + (q >> 5) * 64 + (q & 31)) * ldb + koff + cch * 8;
  const size_t dA1 = (size_t)128 * lda, dA2 = (size_t)64 * lda, dA3 = (size_t)192 * lda;
  const size_t dB1 = (size_t)128 * ldb, dB2 = (size_t)32 * ldb, dB3 = (size_t)160 * ldb;

  // ---- read-side offsets (shorts)
  const int xorv = l15 & 7;
  const int ofss[2] = { (l4 ^ xorv) * 8, ((4 + l4) ^ xorv) * 8 };
  const int abase = (wr * 64 + l15) * 64;            // + mh*8192 + i*1024
  const int bbase = 16384 + (wc * 32 + l15) * 64;    // + nh*8192 + j*1024

#define STA(d_, bb_, r_) gload16(gA0 + (d_), &lds[(bb_) * 32768 + (r_) * 4096 + w * 512])
#define STB(d_, bb_, r_) gload16(gB0 + (d_), &lds[(bb_) * 32768 + 16384 + (r_) * 4096 + w * 512])
#define RDA(bb_, mh_, i_, s_) (*(const s16x8*)&lds[(bb_) * 32768 + (mh_) * 8192 + abase + (i_) * 1024 + ofss[s_]])
#define RDB(bb_, nh_, j_, s_) (*(const s16x8*)&lds[(bb_) * 32768 + (nh_) * 8192 + bbase + (j_) * 1024 + ofss[s_]])
#define MFMA(a_, b_, c_) c_ = __builtin_amdgcn_mfma_f32_16x16x32_bf16(a_, b_, c_, 0, 0, 0)

  f32x4 acc[8][4];
  #pragma unroll
  for (int m = 0; m < 8; ++m)
    #pragma unroll
    for (int n = 0; n < 4; ++n)
      acc[m][n] = f32x4{0.f, 0.f, 0.f, 0.f};

  // prologue: stage tile 0 (G1 then G2) into buf 0
  STA(0, 0, 0); STA(dA1, 0, 1); STB(0, 0, 0); STB(dB1, 0, 1);
  STA(dA2, 0, 2); STA(dA3, 0, 3); STB(dB2, 0, 2); STB(dB3, 0, 3);
  gA0 += 64; gB0 += 64;
  asm volatile("s_waitcnt vmcnt(4)" ::: "memory");   // G1(t0) landed; G2(t0) in flight
  bar();

  for (int kt = 0; kt < NT; ++kt) {
    const int bb = kt & 1, sb = bb ^ 1;
    const bool st = (kt + 1 < NT);
    s16x8 af[4][2], ag[4][2], b0[2][2], b1[2][2];

    // ---- P1: read A-mh0 (8) + B-nh0 (4); stage G1(t+1); MFMA quad (m0,n0)
    #pragma unroll
    for (int i = 0; i < 4; ++i) { af[i][0] = RDA(bb, 0, i, 0); af[i][1] = RDA(bb, 0, i, 1); }
    #pragma unroll
    for (int j = 0; j < 2; ++j) { b0[j][0] = RDB(bb, 0, j, 0); b0[j][1] = RDB(bb, 0, j, 1); }
    if (st) { STA(0, sb, 0); STA(dA1, sb, 1); STB(0, sb, 0); STB(dB1, sb, 1); }
    bar();
    __builtin_amdgcn_s_setprio(1);
    #pragma unroll
    for (int i = 0; i < 4; ++i)
      #pragma unroll
      for (int j = 0; j < 2; ++j) { MFMA(af[i][0], b0[j][0], acc[i][j]); MFMA(af[i][1], b0[j][1], acc[i][j]); }
    __builtin_amdgcn_s_setprio(0);
    if (st) asm volatile("s_waitcnt vmcnt(4)" ::: "memory");   // G2(t) landed
    else    asm volatile("s_waitcnt vmcnt(0)" ::: "memory");
    bar();

    // ---- P2: read B-nh1 (4); stage G2(t+1); MFMA quad (m0,n1)
    #pragma unroll
    for (int j = 0; j < 2; ++j) { b1[j][0] = RDB(bb, 1, j, 0); b1[j][1] = RDB(bb, 1, j, 1); }
    if (st) { STA(dA2, sb, 2); STA(dA3, sb, 3); STB(dB2, sb, 2); STB(dB3, sb, 3); gA0 += 64; gB0 += 64; }
    bar();
    __builtin_amdgcn_s_setprio(1);
    #pragma unroll
    for (int i = 0; i < 4; ++i)
      #pragma unroll
      for (int j = 0; j < 2; ++j) { MFMA(af[i][0], b1[j][0], acc[i][2 + j]); MFMA(af[i][1], b1[j][1], acc[i][2 + j]); }
    __builtin_amdgcn_s_setprio(0);
    bar();

    // ---- P3: read A-mh1 (8); MFMA quad (m1,n1)
    #pragma unroll
    for (int i = 0; i < 4; ++i) { ag[i][0] = RDA(bb, 1, i, 0); ag[i][1] = RDA(bb, 1, i, 1); }
    bar();
    __builtin_amdgcn_s_setprio(1);
    #pragma unroll
    for (int i = 0; i < 4; ++i)
      #pragma unroll
      for (int j = 0; j < 2; ++j) { MFMA(ag[i][0], b1[j][0], acc[4 + i][2 + j]); MFMA(ag[i][1], b1[j][1], acc[4 + i][2 + j]); }
    __builtin_amdgcn_s_setprio(0);
    bar();

    // ---- P4: no reads (bf0 still live); MFMA quad (m1,n0)
    __builtin_amdgcn_s_setprio(1);
    #pragma unroll
    for (int i = 0; i < 4; ++i)
      #pragma unroll
      for (int j = 0; j < 2; ++j) { MFMA(ag[i][0], b0[j][0], acc[4 + i][j]); MFMA(ag[i][1], b0[j][1], acc[4 + i][j]); }
    __builtin_amdgcn_s_setprio(0);
    if (st) asm volatile("s_waitcnt vmcnt(4)" ::: "memory");   // G1(t+1) landed
    else    asm volatile("s_waitcnt vmcnt(0)" ::: "memory");
    bar();
  }

#undef STA
#undef STB
#undef RDA
#undef RDB
#undef MFMA

  const int rbase = byy * 256 + wr * 128;
  const int cbase = bxx * 256 + wc * 64;

  if (EPI == 2) {
    #pragma unroll
    for (int m = 0; m < 8; ++m) {
      #pragma unroll
      for (int r = 0; r < 4; ++r) {
        const int grow = rbase + m * 16 + l4 * 4 + r;
        float rs = 0.f;
        #pragma unroll
        for (int n = 0; n < 4; ++n) {
          float p = __expf(fast_tanh(acc[m][n][r]) * 0.03125f);
          rs += p;
          Cb[(size_t)grow * ldc + (cbase + n * 16 + l15)] = to_bf16(p);
        }
        rs += __shfl_xor(rs, 1);
        rs += __shfl_xor(rs, 2);
        rs += __shfl_xor(rs, 4);
        rs += __shfl_xor(rs, 8);
        if (l15 == 0) atomicAdd(&rowsum[grow], rs);
      }
    }
  } else if (EPI == 3) {
    float* pdst = part + (size_t)kc * (N_TOK * DIM);
    #pragma unroll
    for (int m = 0; m < 8; ++m) {
      #pragma unroll
      for (int r = 0; r < 4; ++r) {
        const int grow = rbase + m * 16 + l4 * 4 + r;
        if (mode) {
          #pragma unroll
          for (int n = 0; n < 4; ++n)
            pdst[(size_t)grow * ldc + (cbase + n * 16 + l15)] = acc[m][n][r];
        } else {
          const float invl = 1.f / lsum[grow];
          #pragma unroll
          for (int n = 0; n < 4; ++n)
            atomicAdd(&outF[(size_t)grow * ldc + (cbase + n * 16 + l15)], acc[m][n][r] * invl);
        }
      }
    }
  } else {
    #pragma unroll
    for (int m = 0; m < 8; ++m) {
      #pragma unroll
      for (int r = 0; r < 4; ++r) {
        const int grow = rbase + m * 16 + l4 * 4 + r;
        #pragma unroll
        for (int n = 0; n < 4; ++n) {
          const int gcol = cbase + n * 16 + l15;
          const float bias = (EPI == 0) ? aux[gcol] : aux[grow];
          Cb[(size_t)grow * ldc + gcol] = to_bf16(acc[m][n][r] + bias);
        }
      }
    }
  }
}

// ---------------- reduce: out = (p0+p1+p2+p3) / lsum[row] ----------------
__global__ void reduce_pv(const float* __restrict__ part, const float* __restrict__ lsum,
                          float* __restrict__ out) {
  const int i = blockIdx.x * blockDim.x + threadIdx.x;   // float4 index, DIM/4=256 per row
  const float4* p0 = (const float4*)part;
  const float4* p1 = p0 + (N_TOK * DIM / 4);
  const float4* p2 = p1 + (N_TOK * DIM / 4);
  const float4* p3 = p2 + (N_TOK * DIM / 4);
  float4 a = p0[i], b = p1[i], c = p2[i], d = p3[i];
  const float invl = 1.f / lsum[i >> 8];
  float4 o;
  o.x = (a.x + b.x + c.x + d.x) * invl;
  o.y = (a.y + b.y + c.y + d.y) * invl;
  o.z = (a.z + b.z + c.z + d.z) * invl;
  o.w = (a.w + b.w + c.w + d.w) * invl;
  ((float4*)out)[i] = o;
}

extern "C" void kernel_launch(void* const* d_in, const int* in_sizes, int n_in,
                              void* d_out, int out_size, void* d_ws, size_t ws_size,
                              hipStream_t stream) {
  const float* x  = (const float*)d_in[0];
  const float* Wq = (const float*)d_in[1];
  const float* bq = (const float*)d_in[2];
  const float* Wk = (const float*)d_in[3];
  const float* bk = (const float*)d_in[4];
  const float* Wv = (const float*)d_in[5];
  const float* bv = (const float*)d_in[6];
  float* out = (float*)d_out;

  char* ws = (char*)d_ws;
  short* xb   = (short*)(ws);                      //  8 MB  x bf16 [4096][1024]
  short* qk   = (short*)(ws + (8ull  << 20));      // 16 MB  q|k bf16 [4096][2048]
  short* vTb  = (short*)(ws + (24ull << 20));      //  8 MB  v^T [1024][4096]
  short* WqkT = (short*)(ws + (32ull << 20));      //  4 MB  [2048][1024]
  short* WvT  = (short*)(ws + (36ull << 20));      //  2 MB
  float* bqk  = (float*)(ws + (38ull << 20));      //  8 KB
  float* lsum = (float*)(ws + (39ull << 20));      // 16 KB
  short* P    = (short*)(ws + (40ull << 20));      // 32 MB  P bf16 [4096][4096]
  float* part = (float*)(ws + (72ull << 20));      // 67 MB  (optional) 4x[4096][1024] f32

  const size_t need = (72ull << 20) + 4ull * N_TOK * DIM * sizeof(float);
  const int mode = (ws_size >= need) ? 1 : 0;      // 1: ws partials + reduce; 0: atomics

  hipMemsetAsync(lsum, 0, N_TOK * sizeof(float), stream);
  if (!mode) hipMemsetAsync(out, 0, (size_t)N_TOK * DIM * sizeof(float), stream);

  hipMemcpyAsync(bqk,        bq, DIM * sizeof(float), hipMemcpyDeviceToDevice, stream);
  hipMemcpyAsync(bqk + DIM,  bk, DIM * sizeof(float), hipMemcpyDeviceToDevice, stream);

  cast_bf16_kernel<<<(N_TOK * DIM / 4 + 255) / 256, 256, 0, stream>>>(x, xb, N_TOK * DIM);
  dim3 tgrid(DIM / 32, DIM / 32), tblk(32, 8);
  transpose_cast_kernel<<<tgrid, tblk, 0, stream>>>(Wq, WqkT, DIM, DIM);
  transpose_cast_kernel<<<tgrid, tblk, 0, stream>>>(Wk, WqkT + DIM * DIM, DIM, DIM);
  transpose_cast_kernel<<<tgrid, tblk, 0, stream>>>(Wv, WvT, DIM, DIM);

  // q|k projection: [4096][2048] = x @ [WqT;WkT]^T + bqk   (grid 16x8 = 128)
  gemm8p<0><<<dim3(128), dim3(512), 0, stream>>>(
      xb, WqkT, DIM, DIM, 16, 8, 2 * DIM, bqk, qk, nullptr, nullptr, nullptr, nullptr, 0);
  // vT = WvT @ x^T + bv[row]   (M=1024, N=4096 ; grid 4x16 = 64)
  gemm8p<1><<<dim3(64), dim3(512), 0, stream>>>(
      WvT, xb, DIM, DIM, 16, 16, N_TOK, bv, vTb, nullptr, nullptr, nullptr, nullptr, 0);
  // P = exp(tanh(q k^T)/32) + rowsum   (grid 16x16 = 256)
  gemm8p<2><<<dim3(256), dim3(512), 0, stream>>>(
      qk, qk + DIM, 2 * DIM, 2 * DIM, 16, 16, N_TOK, nullptr, P, nullptr, nullptr, lsum, nullptr, 0);
  // PV split-K=4   (grid 16 x 4 x 4 = 256)
  gemm8p<3><<<dim3(256), dim3(512), 0, stream>>>(
      P, vTb, N_TOK, N_TOK, 16, 4, DIM, nullptr, nullptr, out, lsum, nullptr, part, mode);
  if (mode)
    reduce_pv<<<dim3(N_TOK * DIM / 4 / 256), dim3(256), 0, stream>>>(part, lsum, out);
}

// Round 6
// 163.965 us; speedup vs baseline: 1.1590x; 1.1590x over previous
//
#include <hip/hip_runtime.h>
#include <hip/hip_bf16.h>
#include <math.h>

#define N_TOK 4096
#define DIM   1024

typedef __attribute__((ext_vector_type(8))) short s16x8;
typedef __attribute__((ext_vector_type(4))) float f32x4;

__device__ inline short to_bf16(float f) {
  union { float f; unsigned u; } v; v.f = f;
  unsigned r = v.u + 0x7FFFu + ((v.u >> 16) & 1u);   // RNE
  return (short)(r >> 16);
}

__device__ inline void gload16(const short* g, short* l) {
  __builtin_amdgcn_global_load_lds(
      (const __attribute__((address_space(1))) unsigned int*)g,
      (__attribute__((address_space(3))) unsigned int*)l, 16, 0, 0);
}

// ---------------- cast fp32 -> bf16 ----------------
__global__ void cast_bf16_kernel(const float* __restrict__ in, short* __restrict__ out, int n) {
  int i = (blockIdx.x * blockDim.x + threadIdx.x) * 4;
  if (i >= n) return;
  float4 v = *reinterpret_cast<const float4*>(in + i);
  short4 o;
  o.x = to_bf16(v.x); o.y = to_bf16(v.y); o.z = to_bf16(v.z); o.w = to_bf16(v.w);
  *reinterpret_cast<short4*>(out + i) = o;
}

// ---------------- transpose + cast: in[R][C] fp32 -> out[C][R] bf16 ----------------
__global__ void transpose_cast_kernel(const float* __restrict__ in, short* __restrict__ out,
                                      int R, int C) {
  __shared__ float tile[32][33];
  int bx = blockIdx.x * 32, by = blockIdx.y * 32;
  int tx = threadIdx.x, ty = threadIdx.y;   // block (32,8)
  #pragma unroll
  for (int i = 0; i < 32; i += 8)
    tile[ty + i][tx] = in[(size_t)(by + ty + i) * C + (bx + tx)];
  __syncthreads();
  #pragma unroll
  for (int i = 0; i < 32; i += 8)
    out[(size_t)(bx + ty + i) * R + (by + tx)] = to_bf16(tile[tx][ty + i]);
}

__device__ inline float fast_tanh(float x) {
  float e = __expf(2.0f * x);
  return 1.0f - 2.0f / (e + 1.0f);
}

// ============== m97-structure 128x128 NT GEMM, BK=64, global_load_lds ==============
// C[M][N] = A[M,K] @ B[N,K]^T. 256 threads (4 waves, 2x2), 3 blocks/CU.
// 2 barriers per K-tile: stage -> sync -> compute -> sync. TLP hides the drain.
// LDS chunk swizzle: data 16B-chunk c of row r stored at phys chunk c ^ (r&7);
// achieved with linear LDS dest + pre-inverse-swizzled global source (both-sides rule).
// EPI 0: +bias[col] -> bf16 ; EPI 1: +bias[row] -> bf16
// EPI 2: P=exp(tanh(.)/32) -> bf16 + atomic rowsum
// EPI 3: PV split-K (blockIdx.z): mode1 -> part[kc]; mode0 -> atomicAdd(out, acc/l)
template<int EPI>
__global__ __launch_bounds__(256, 3)
void gemm128(const short* __restrict__ A, const short* __restrict__ B,
             int lda, int ldb, int ldc, int NT,
             const float* __restrict__ aux, short* __restrict__ Cb,
             float* __restrict__ outF, const float* __restrict__ lsum,
             float* __restrict__ rowsum, float* __restrict__ part, int mode)
{
  __shared__ short As[128 * 64];
  __shared__ short Bs[128 * 64];
  const int t    = threadIdx.x;
  const int lane = t & 63;
  const int wid  = t >> 6;          // 4 waves: 2(M) x 2(N)
  const int wr   = wid >> 1, wc = wid & 1;
  const int l15  = lane & 15, l4 = lane >> 4;

  // bijective XCD swizzle over the linearized grid (total % 8 == 0 for all launches)
  const int nx = gridDim.x, ny = gridDim.y;
  int lin = ((int)blockIdx.z * ny + blockIdx.y) * nx + blockIdx.x;
  const int tot = nx * ny * (int)gridDim.z;
  int swz = (lin & 7) * (tot >> 3) + (lin >> 3);
  const int bxx = swz % nx; swz /= nx;
  const int byy = swz % ny;
  const int kc  = swz / ny;
  const int koff = kc * NT * 64;

  // staging: thread t -> row srow(+32i), phys chunk t&7; source chunk pre-inverse-swizzled
  const int srow = t >> 3;
  const int sch  = ((t & 7) ^ (srow & 7)) * 8;
  const short* gA = A + (size_t)(byy * 128 + srow) * lda + koff + sch;
  const short* gB = B + (size_t)(bxx * 128 + srow) * ldb + koff + sch;

  f32x4 acc[4][4];
  #pragma unroll
  for (int m = 0; m < 4; ++m)
    #pragma unroll
    for (int n = 0; n < 4; ++n)
      acc[m][n] = f32x4{0.f, 0.f, 0.f, 0.f};

  for (int kt = 0; kt < NT; ++kt) {
    // ---- stage tile kt (8 x global_load_lds_dwordx4 per thread-slot) ----
    #pragma unroll
    for (int i = 0; i < 4; ++i) {
      gload16(gA + (size_t)(i * 32) * lda + kt * 64, &As[i * 2048 + t * 8]);
      gload16(gB + (size_t)(i * 32) * ldb + kt * 64, &Bs[i * 2048 + t * 8]);
    }
    __syncthreads();    // drains vmcnt -> tile visible to all waves
    // ---- compute: 16 ds_read_b128 + 32 MFMA per wave ----
    #pragma unroll
    for (int kk = 0; kk < 2; ++kk) {
      s16x8 af[4], bf[4];
      #pragma unroll
      for (int m = 0; m < 4; ++m)
        af[m] = *(const s16x8*)&As[(wr * 64 + m * 16 + l15) * 64 + ((kk * 4 + l4) ^ (l15 & 7)) * 8];
      #pragma unroll
      for (int n = 0; n < 4; ++n)
        bf[n] = *(const s16x8*)&Bs[(wc * 64 + n * 16 + l15) * 64 + ((kk * 4 + l4) ^ (l15 & 7)) * 8];
      #pragma unroll
      for (int m = 0; m < 4; ++m)
        #pragma unroll
        for (int n = 0; n < 4; ++n)
          acc[m][n] = __builtin_amdgcn_mfma_f32_16x16x32_bf16(af[m], bf[n], acc[m][n], 0, 0, 0);
    }
    __syncthreads();    // reads done before next tile's staging overwrites
  }

  const int rbase = byy * 128 + wr * 64;
  const int cbase = bxx * 128 + wc * 64;

  if (EPI == 2) {
    #pragma unroll
    for (int m = 0; m < 4; ++m) {
      #pragma unroll
      for (int r = 0; r < 4; ++r) {
        const int grow = rbase + m * 16 + l4 * 4 + r;
        float rs = 0.f;
        #pragma unroll
        for (int n = 0; n < 4; ++n) {
          float p = __expf(fast_tanh(acc[m][n][r]) * 0.03125f);
          rs += p;
          Cb[(size_t)grow * ldc + (cbase + n * 16 + l15)] = to_bf16(p);
        }
        rs += __shfl_xor(rs, 1);
        rs += __shfl_xor(rs, 2);
        rs += __shfl_xor(rs, 4);
        rs += __shfl_xor(rs, 8);
        if (l15 == 0) atomicAdd(&rowsum[grow], rs);
      }
    }
  } else if (EPI == 3) {
    float* pdst = part + (size_t)kc * (N_TOK * DIM);
    #pragma unroll
    for (int m = 0; m < 4; ++m) {
      #pragma unroll
      for (int r = 0; r < 4; ++r) {
        const int grow = rbase + m * 16 + l4 * 4 + r;
        if (mode) {
          #pragma unroll
          for (int n = 0; n < 4; ++n)
            pdst[(size_t)grow * ldc + (cbase + n * 16 + l15)] = acc[m][n][r];
        } else {
          const float invl = 1.f / lsum[grow];
          #pragma unroll
          for (int n = 0; n < 4; ++n)
            atomicAdd(&outF[(size_t)grow * ldc + (cbase + n * 16 + l15)], acc[m][n][r] * invl);
        }
      }
    }
  } else {
    #pragma unroll
    for (int m = 0; m < 4; ++m) {
      #pragma unroll
      for (int r = 0; r < 4; ++r) {
        const int grow = rbase + m * 16 + l4 * 4 + r;
        #pragma unroll
        for (int n = 0; n < 4; ++n) {
          const int gcol = cbase + n * 16 + l15;
          const float bias = (EPI == 0) ? aux[gcol] : aux[grow];
          Cb[(size_t)grow * ldc + gcol] = to_bf16(acc[m][n][r] + bias);
        }
      }
    }
  }
}

// ---------------- reduce: out = (p0+p1+p2+p3) / lsum[row] ----------------
__global__ void reduce_pv(const float* __restrict__ part, const float* __restrict__ lsum,
                          float* __restrict__ out) {
  const int i = blockIdx.x * blockDim.x + threadIdx.x;   // float4 index, DIM/4=256 per row
  const float4* p0 = (const float4*)part;
  const float4* p1 = p0 + (N_TOK * DIM / 4);
  const float4* p2 = p1 + (N_TOK * DIM / 4);
  const float4* p3 = p2 + (N_TOK * DIM / 4);
  float4 a = p0[i], b = p1[i], c = p2[i], d = p3[i];
  const float invl = 1.f / lsum[i >> 8];
  float4 o;
  o.x = (a.x + b.x + c.x + d.x) * invl;
  o.y = (a.y + b.y + c.y + d.y) * invl;
  o.z = (a.z + b.z + c.z + d.z) * invl;
  o.w = (a.w + b.w + c.w + d.w) * invl;
  ((float4*)out)[i] = o;
}

extern "C" void kernel_launch(void* const* d_in, const int* in_sizes, int n_in,
                              void* d_out, int out_size, void* d_ws, size_t ws_size,
                              hipStream_t stream) {
  const float* x  = (const float*)d_in[0];
  const float* Wq = (const float*)d_in[1];
  const float* bq = (const float*)d_in[2];
  const float* Wk = (const float*)d_in[3];
  const float* bk = (const float*)d_in[4];
  const float* Wv = (const float*)d_in[5];
  const float* bv = (const float*)d_in[6];
  float* out = (float*)d_out;

  char* ws = (char*)d_ws;
  short* xb   = (short*)(ws);                      //  8 MB  x bf16 [4096][1024]
  short* qk   = (short*)(ws + (8ull  << 20));      // 16 MB  q|k bf16 [4096][2048]
  short* vTb  = (short*)(ws + (24ull << 20));      //  8 MB  v^T [1024][4096]
  short* WqkT = (short*)(ws + (32ull << 20));      //  4 MB  [2048][1024]
  short* WvT  = (short*)(ws + (36ull << 20));      //  2 MB
  float* bqk  = (float*)(ws + (38ull << 20));      //  8 KB
  float* lsum = (float*)(ws + (39ull << 20));      // 16 KB
  short* P    = (short*)(ws + (40ull << 20));      // 32 MB  P bf16 [4096][4096]
  float* part = (float*)(ws + (72ull << 20));      // 67 MB  (optional) 4x[4096][1024] f32

  const size_t need = (72ull << 20) + 4ull * N_TOK * DIM * sizeof(float);
  const int mode = (ws_size >= need) ? 1 : 0;

  hipMemsetAsync(lsum, 0, N_TOK * sizeof(float), stream);
  if (!mode) hipMemsetAsync(out, 0, (size_t)N_TOK * DIM * sizeof(float), stream);

  hipMemcpyAsync(bqk,        bq, DIM * sizeof(float), hipMemcpyDeviceToDevice, stream);
  hipMemcpyAsync(bqk + DIM,  bk, DIM * sizeof(float), hipMemcpyDeviceToDevice, stream);

  cast_bf16_kernel<<<(N_TOK * DIM / 4 + 255) / 256, 256, 0, stream>>>(x, xb, N_TOK * DIM);
  dim3 tgrid(DIM / 32, DIM / 32), tblk(32, 8);
  transpose_cast_kernel<<<tgrid, tblk, 0, stream>>>(Wq, WqkT, DIM, DIM);
  transpose_cast_kernel<<<tgrid, tblk, 0, stream>>>(Wk, WqkT + DIM * DIM, DIM, DIM);
  transpose_cast_kernel<<<tgrid, tblk, 0, stream>>>(Wv, WvT, DIM, DIM);

  dim3 blk(256);
  // q|k projection: [4096][2048] = x @ [WqT;WkT]^T + bqk   (grid 16x32 = 512)
  gemm128<0><<<dim3(16, 32), blk, 0, stream>>>(
      xb, WqkT, DIM, DIM, 2 * DIM, 16, bqk, qk, nullptr, nullptr, nullptr, nullptr, 0);
  // vT = WvT @ x^T + bv[row]   (M=1024, N=4096 ; grid 32x8 = 256)
  gemm128<1><<<dim3(32, 8), blk, 0, stream>>>(
      WvT, xb, DIM, DIM, N_TOK, 16, bv, vTb, nullptr, nullptr, nullptr, nullptr, 0);
  // P = exp(tanh(q k^T)/32) + rowsum   (grid 32x32 = 1024)
  gemm128<2><<<dim3(32, 32), blk, 0, stream>>>(
      qk, qk + DIM, 2 * DIM, 2 * DIM, N_TOK, 16, nullptr, P, nullptr, nullptr, lsum, nullptr, 0);
  // PV split-K=4   (grid 8 x 32 x 4 = 1024)
  gemm128<3><<<dim3(8, 32, 4), blk, 0, stream>>>(
      P, vTb, N_TOK, N_TOK, DIM, 16, nullptr, nullptr, out, lsum, nullptr, part, mode);
  if (mode)
    reduce_pv<<<dim3(N_TOK * DIM / 4 / 256), dim3(256), 0, stream>>>(part, lsum, out);
}

// Round 8
// 155.326 us; speedup vs baseline: 1.2234x; 1.0556x over previous
//
#include <hip/hip_runtime.h>
#include <hip/hip_bf16.h>
#include <math.h>

#define N_TOK 4096
#define DIM   1024

typedef __attribute__((ext_vector_type(8))) short s16x8;
typedef __attribute__((ext_vector_type(4))) float f32x4;
typedef __attribute__((ext_vector_type(8))) float f32x8;

__device__ inline short to_bf16(float f) {
  union { float f; unsigned u; } v; v.f = f;
  unsigned r = v.u + 0x7FFFu + ((v.u >> 16) & 1u);   // RNE
  return (short)(r >> 16);
}

__device__ inline float bf2f(short s) {
  union { unsigned u; float f; } v; v.u = ((unsigned)(unsigned short)s) << 16;
  return v.f;
}

__device__ inline void gload16(const short* g, short* l) {
  __builtin_amdgcn_global_load_lds(
      (const __attribute__((address_space(1))) unsigned int*)g,
      (__attribute__((address_space(3))) unsigned int*)l, 16, 0, 0);
}

// ---------------- cast fp32 -> bf16 ----------------
__global__ void cast_bf16_kernel(const float* __restrict__ in, short* __restrict__ out, int n) {
  int i = (blockIdx.x * blockDim.x + threadIdx.x) * 4;
  if (i >= n) return;
  float4 v = *reinterpret_cast<const float4*>(in + i);
  short4 o;
  o.x = to_bf16(v.x); o.y = to_bf16(v.y); o.z = to_bf16(v.z); o.w = to_bf16(v.w);
  *reinterpret_cast<short4*>(out + i) = o;
}

// ---------------- transpose + cast: in[R][C] fp32 -> out[C][R] bf16 ----------------
__global__ void transpose_cast_kernel(const float* __restrict__ in, short* __restrict__ out,
                                      int R, int C) {
  __shared__ float tile[32][33];
  int bx = blockIdx.x * 32, by = blockIdx.y * 32;
  int tx = threadIdx.x, ty = threadIdx.y;   // block (32,8)
  #pragma unroll
  for (int i = 0; i < 32; i += 8)
    tile[ty + i][tx] = in[(size_t)(by + ty + i) * C + (bx + tx)];
  __syncthreads();
  #pragma unroll
  for (int i = 0; i < 32; i += 8)
    out[(size_t)(bx + ty + i) * R + (by + tx)] = to_bf16(tile[tx][ty + i]);
}

__device__ inline float fast_tanh(float x) {
  float e = __expf(2.0f * x);
  return 1.0f - 2.0f / (e + 1.0f);
}

// ============== m97-structure 128x128 NT GEMM, BK=64, global_load_lds ==============
// C[M][N] = A[M,K] @ B[N,K]^T. 256 threads (4 waves, 2x2), 4 blocks/CU (TLP hides
// the barrier drain). 2 barriers per K-tile.
// LDS chunk swizzle: data 16B-chunk c of row r stored at phys chunk c ^ (r&7);
// linear LDS dest + pre-inverse-swizzled global source (both-sides rule).
// EPI 0: +bias[col] -> bf16 ; EPI 1: +bias[row] -> bf16
// EPI 2: P=exp(tanh(.)/32) -> bf16 + atomic rowsum
// EPI 3: PV split-K (z): mode1 -> part[kc] (bf16); mode0 -> atomicAdd(out, acc/l)
template<int EPI>
__global__ __launch_bounds__(256, 4)
void gemm128(const short* __restrict__ A, const short* __restrict__ B,
             int lda, int ldb, int ldc, int NT,
             const float* __restrict__ aux, short* __restrict__ Cb,
             float* __restrict__ outF, const float* __restrict__ lsum,
             float* __restrict__ rowsum, short* __restrict__ part, int mode)
{
  __shared__ short As[128 * 64];
  __shared__ short Bs[128 * 64];
  const int t    = threadIdx.x;
  const int lane = t & 63;
  const int wid  = t >> 6;          // 4 waves: 2(M) x 2(N)
  const int wr   = wid >> 1, wc = wid & 1;
  const int l15  = lane & 15, l4 = lane >> 4;

  // bijective XCD swizzle over the linearized grid (total % 8 == 0 for all launches)
  const int nx = gridDim.x, ny = gridDim.y;
  int lin = ((int)blockIdx.z * ny + blockIdx.y) * nx + blockIdx.x;
  const int tot = nx * ny * (int)gridDim.z;
  int swz = (lin & 7) * (tot >> 3) + (lin >> 3);
  const int bxx = swz % nx; swz /= nx;
  const int byy = swz % ny;
  const int kc  = swz / ny;
  const int koff = kc * NT * 64;

  // staging: thread t -> row srow(+32i), phys chunk t&7; source chunk pre-inverse-swizzled
  const int srow = t >> 3;
  const int sch  = ((t & 7) ^ (srow & 7)) * 8;
  const short* gA = A + (size_t)(byy * 128 + srow) * lda + koff + sch;
  const short* gB = B + (size_t)(bxx * 128 + srow) * ldb + koff + sch;

  f32x4 acc[4][4];
  #pragma unroll
  for (int m = 0; m < 4; ++m)
    #pragma unroll
    for (int n = 0; n < 4; ++n)
      acc[m][n] = f32x4{0.f, 0.f, 0.f, 0.f};

  for (int kt = 0; kt < NT; ++kt) {
    // ---- stage tile kt (8 x global_load_lds_dwordx4 per thread) ----
    #pragma unroll
    for (int i = 0; i < 4; ++i) {
      gload16(gA + (size_t)(i * 32) * lda + kt * 64, &As[i * 2048 + t * 8]);
      gload16(gB + (size_t)(i * 32) * ldb + kt * 64, &Bs[i * 2048 + t * 8]);
    }
    __syncthreads();    // drains vmcnt -> tile visible to all waves
    // ---- compute: 16 ds_read_b128 + 32 MFMA per wave ----
    #pragma unroll
    for (int kk = 0; kk < 2; ++kk) {
      s16x8 af[4], bf[4];
      #pragma unroll
      for (int m = 0; m < 4; ++m)
        af[m] = *(const s16x8*)&As[(wr * 64 + m * 16 + l15) * 64 + ((kk * 4 + l4) ^ (l15 & 7)) * 8];
      #pragma unroll
      for (int n = 0; n < 4; ++n)
        bf[n] = *(const s16x8*)&Bs[(wc * 64 + n * 16 + l15) * 64 + ((kk * 4 + l4) ^ (l15 & 7)) * 8];
      #pragma unroll
      for (int m = 0; m < 4; ++m)
        #pragma unroll
        for (int n = 0; n < 4; ++n)
          acc[m][n] = __builtin_amdgcn_mfma_f32_16x16x32_bf16(af[m], bf[n], acc[m][n], 0, 0, 0);
    }
    __syncthreads();    // reads done before next tile's staging overwrites
  }

  const int rbase = byy * 128 + wr * 64;
  const int cbase = bxx * 128 + wc * 64;

  if (EPI == 2) {
    #pragma unroll
    for (int m = 0; m < 4; ++m) {
      #pragma unroll
      for (int r = 0; r < 4; ++r) {
        const int grow = rbase + m * 16 + l4 * 4 + r;
        float rs = 0.f;
        #pragma unroll
        for (int n = 0; n < 4; ++n) {
          float p = __expf(fast_tanh(acc[m][n][r]) * 0.03125f);
          rs += p;
          Cb[(size_t)grow * ldc + (cbase + n * 16 + l15)] = to_bf16(p);
        }
        rs += __shfl_xor(rs, 1);
        rs += __shfl_xor(rs, 2);
        rs += __shfl_xor(rs, 4);
        rs += __shfl_xor(rs, 8);
        if (l15 == 0) atomicAdd(&rowsum[grow], rs);
      }
    }
  } else if (EPI == 3) {
    short* pdst = part + (size_t)kc * (N_TOK * DIM);
    #pragma unroll
    for (int m = 0; m < 4; ++m) {
      #pragma unroll
      for (int r = 0; r < 4; ++r) {
        const int grow = rbase + m * 16 + l4 * 4 + r;
        if (mode) {
          #pragma unroll
          for (int n = 0; n < 4; ++n)
            pdst[(size_t)grow * ldc + (cbase + n * 16 + l15)] = to_bf16(acc[m][n][r]);
        } else {
          const float invl = 1.f / lsum[grow];
          #pragma unroll
          for (int n = 0; n < 4; ++n)
            atomicAdd(&outF[(size_t)grow * ldc + (cbase + n * 16 + l15)], acc[m][n][r] * invl);
        }
      }
    }
  } else {
    #pragma unroll
    for (int m = 0; m < 4; ++m) {
      #pragma unroll
      for (int r = 0; r < 4; ++r) {
        const int grow = rbase + m * 16 + l4 * 4 + r;
        #pragma unroll
        for (int n = 0; n < 4; ++n) {
          const int gcol = cbase + n * 16 + l15;
          const float bias = (EPI == 0) ? aux[gcol] : aux[grow];
          Cb[(size_t)grow * ldc + gcol] = to_bf16(acc[m][n][r] + bias);
        }
      }
    }
  }
}

// -------- reduce: out = (p0+p1+p2+p3) / lsum[row], partials bf16, 8 elems/thread -----
__global__ void reduce_pv(const short* __restrict__ part, const float* __restrict__ lsum,
                          float* __restrict__ out) {
  const int i = blockIdx.x * blockDim.x + threadIdx.x;   // 8-elem group index
  const int base = i * 8;
  const s16x8* p0 = (const s16x8*)(part) + i;
  const s16x8* p1 = (const s16x8*)(part + (size_t)N_TOK * DIM) + i;
  const s16x8* p2 = (const s16x8*)(part + (size_t)2 * N_TOK * DIM) + i;
  const s16x8* p3 = (const s16x8*)(part + (size_t)3 * N_TOK * DIM) + i;
  s16x8 a = *p0, b = *p1, c = *p2, d = *p3;
  const float invl = 1.f / lsum[base >> 10];             // row = base / DIM
  f32x8 o;
  #pragma unroll
  for (int j = 0; j < 8; ++j)
    o[j] = (bf2f(a[j]) + bf2f(b[j]) + bf2f(c[j]) + bf2f(d[j])) * invl;
  *reinterpret_cast<f32x8*>(out + base) = o;
}

extern "C" void kernel_launch(void* const* d_in, const int* in_sizes, int n_in,
                              void* d_out, int out_size, void* d_ws, size_t ws_size,
                              hipStream_t stream) {
  const float* x  = (const float*)d_in[0];
  const float* Wq = (const float*)d_in[1];
  const float* bq = (const float*)d_in[2];
  const float* Wk = (const float*)d_in[3];
  const float* bk = (const float*)d_in[4];
  const float* Wv = (const float*)d_in[5];
  const float* bv = (const float*)d_in[6];
  float* out = (float*)d_out;

  char* ws = (char*)d_ws;
  short* xb   = (short*)(ws);                      //  8 MB  x bf16 [4096][1024]
  short* qk   = (short*)(ws + (8ull  << 20));      // 16 MB  q|k bf16 [4096][2048]
  short* vTb  = (short*)(ws + (24ull << 20));      //  8 MB  v^T [1024][4096]
  short* WqkT = (short*)(ws + (32ull << 20));      //  4 MB  [2048][1024]
  short* WvT  = (short*)(ws + (36ull << 20));      //  2 MB
  float* bqk  = (float*)(ws + (38ull << 20));      //  8 KB
  float* lsum = (float*)(ws + (39ull << 20));      // 16 KB
  short* P    = (short*)(ws + (40ull << 20));      // 32 MB  P bf16 [4096][4096]
  short* part = (short*)(ws + (72ull << 20));      // 33.5 MB (optional) 4x[4096][1024] bf16

  const size_t need = (72ull << 20) + 4ull * N_TOK * DIM * sizeof(short);
  const int mode = (ws_size >= need) ? 1 : 0;

  hipMemsetAsync(lsum, 0, N_TOK * sizeof(float), stream);
  if (!mode) hipMemsetAsync(out, 0, (size_t)N_TOK * DIM * sizeof(float), stream);

  hipMemcpyAsync(bqk,        bq, DIM * sizeof(float), hipMemcpyDeviceToDevice, stream);
  hipMemcpyAsync(bqk + DIM,  bk, DIM * sizeof(float), hipMemcpyDeviceToDevice, stream);

  cast_bf16_kernel<<<(N_TOK * DIM / 4 + 255) / 256, 256, 0, stream>>>(x, xb, N_TOK * DIM);
  dim3 tgrid(DIM / 32, DIM / 32), tblk(32, 8);
  transpose_cast_kernel<<<tgrid, tblk, 0, stream>>>(Wq, WqkT, DIM, DIM);
  transpose_cast_kernel<<<tgrid, tblk, 0, stream>>>(Wk, WqkT + DIM * DIM, DIM, DIM);
  transpose_cast_kernel<<<tgrid, tblk, 0, stream>>>(Wv, WvT, DIM, DIM);

  dim3 blk(256);
  // q|k projection: [4096][2048] = x @ [WqT;WkT]^T + bqk   (grid 16x32 = 512)
  gemm128<0><<<dim3(16, 32), blk, 0, stream>>>(
      xb, WqkT, DIM, DIM, 2 * DIM, 16, bqk, qk, nullptr, nullptr, nullptr, nullptr, 0);
  // vT = WvT @ x^T + bv[row]   (M=1024, N=4096 ; grid 32x8 = 256)
  gemm128<1><<<dim3(32, 8), blk, 0, stream>>>(
      WvT, xb, DIM, DIM, N_TOK, 16, bv, vTb, nullptr, nullptr, nullptr, nullptr, 0);
  // P = exp(tanh(q k^T)/32) + rowsum   (grid 32x32 = 1024, 4 blocks/CU)
  gemm128<2><<<dim3(32, 32), blk, 0, stream>>>(
      qk, qk + DIM, 2 * DIM, 2 * DIM, N_TOK, 16, nullptr, P, nullptr, nullptr, lsum, nullptr, 0);
  // PV split-K=4   (grid 8 x 32 x 4 = 1024, 4 blocks/CU), bf16 partials
  gemm128<3><<<dim3(8, 32, 4), blk, 0, stream>>>(
      P, vTb, N_TOK, N_TOK, DIM, 16, nullptr, nullptr, out, lsum, nullptr, part, mode);
  if (mode)
    reduce_pv<<<dim3(N_TOK * DIM / 8 / 256), dim3(256), 0, stream>>>(part, lsum, out);
}